// Round 2
// baseline (2031.670 us; speedup 1.0000x reference)
//
#include <hip/hip_runtime.h>
#include <hip/hip_bf16.h>

typedef unsigned short u16;
typedef __attribute__((ext_vector_type(8))) short short8;
typedef __attribute__((ext_vector_type(4))) float floatx4;

#define NT 128
#define NB 256
#define NC 512
#define HID 256
#define EMB 128
#define NCLS 37
#define NSTEPS 25
#define POSEC 256
#define RNN_IN 1472

__device__ __forceinline__ float b2f(u16 u) {
    union { float f; unsigned int i; } v; v.i = ((unsigned int)u) << 16; return v.f;
}
__device__ __forceinline__ u16 f2b(float f) {
    union { float f; unsigned int i; } v; v.f = f;
    unsigned int x = v.i;
    return (u16)((x + 0x7fffu + ((x >> 16) & 1u)) >> 16);  // RNE
}
__device__ __forceinline__ float sigm(float x) { return 1.f / (1.f + expf(-x)); }

// dtype-polymorphic loads
__device__ __forceinline__ float ldf(const float* p, size_t i) { return p[i]; }
__device__ __forceinline__ float ldf(const u16* p, size_t i) { return b2f(p[i]); }

__device__ __forceinline__ short8 ld8(const u16* p) { return *(const short8*)p; }
__device__ __forceinline__ short8 ld8(const float* p) {
    float4 a = *(const float4*)p; float4 b = *(const float4*)(p + 4);
    short8 r;
    r[0] = (short)f2b(a.x); r[1] = (short)f2b(a.y); r[2] = (short)f2b(a.z); r[3] = (short)f2b(a.w);
    r[4] = (short)f2b(b.x); r[5] = (short)f2b(b.y); r[6] = (short)f2b(b.z); r[7] = (short)f2b(b.w);
    return r;
}
__device__ __forceinline__ float4 ld4(const float* p) { return *(const float4*)p; }
__device__ __forceinline__ float4 ld4(const u16* p) {
    ushort4 v = *(const ushort4*)p;
    return make_float4(b2f(v.x), b2f(v.y), b2f(v.z), b2f(v.w));
}

// ---------------- dtype probe: bf16 interp of first 128 u16 of score_w is
// small iff data really is bf16 (f32 data -> random-exponent garbage).
__global__ void probe_kernel(const void* score_w, int* flag) {
    __shared__ float red[128];
    int tid = threadIdx.x;  // 128 threads
    const u16* p = (const u16*)score_w;
    float v = fabsf(b2f(p[tid]));
    v = (v == v && v < 1e6f) ? v : 1e6f;  // NaN/inf -> 1e6
    red[tid] = v;
    __syncthreads();
    for (int s2 = 64; s2 > 0; s2 >>= 1) {
        if (tid < s2) red[tid] += red[tid + s2];
        __syncthreads();
    }
    if (tid == 0) flag[0] = (red[0] < 1000.f) ? 1 : 0;  // 1 = bf16
}

// ---------------- canonicalize GRU weights to bf16
__global__ void conv_kernel(const void* w_ih, const void* w_hh,
                            u16* out_ih, u16* out_hh, const int* flagp) {
    int f = *flagp;
    int idx = blockIdx.x * blockDim.x + threadIdx.x;
    int stride = gridDim.x * blockDim.x;
    const int n_ih = 768 * RNN_IN, n_hh = 768 * HID;
    if (f) {
        const u16* a = (const u16*)w_ih; const u16* b = (const u16*)w_hh;
        for (int i = idx; i < n_ih; i += stride) out_ih[i] = a[i];
        for (int i = idx; i < n_hh; i += stride) out_hh[i] = b[i];
    } else {
        const float* a = (const float*)w_ih; const float* b = (const float*)w_hh;
        for (int i = idx; i < n_ih; i += stride) out_ih[i] = f2b(a[i]);
        for (int i = idx; i < n_hh; i += stride) out_hh[i] = f2b(b[i]);
    }
}

// ---------------- feats_proj: fp[t*NB+b][h] = sum_c feats[t*NB+b][c] * i2h_w[h][c]
template <typename T>
__device__ void fp_body(const T* feats, const T* i2h_w, u16* fp) {
    int wave = threadIdx.x >> 6, lane = threadIdx.x & 63;
    int m_base = blockIdx.x * 64 + wave * 16;
    int n_base = blockIdx.y * 64;
    int lr = lane & 15;
    int kq = (lane >> 4) * 8;
    floatx4 acc0 = {0.f, 0.f, 0.f, 0.f}, acc1 = acc0, acc2 = acc0, acc3 = acc0;
    const int mrow = m_base + lr;
    for (int kk = 0; kk < NC; kk += 32) {
        short8 a = ld8(feats + (size_t)mrow * NC + kk + kq);
        short8 b0 = ld8(i2h_w + (size_t)(n_base + lr) * NC + kk + kq);
        short8 b1 = ld8(i2h_w + (size_t)(n_base + 16 + lr) * NC + kk + kq);
        short8 b2 = ld8(i2h_w + (size_t)(n_base + 32 + lr) * NC + kk + kq);
        short8 b3 = ld8(i2h_w + (size_t)(n_base + 48 + lr) * NC + kk + kq);
        acc0 = __builtin_amdgcn_mfma_f32_16x16x32_bf16(a, b0, acc0, 0, 0, 0);
        acc1 = __builtin_amdgcn_mfma_f32_16x16x32_bf16(a, b1, acc1, 0, 0, 0);
        acc2 = __builtin_amdgcn_mfma_f32_16x16x32_bf16(a, b2, acc2, 0, 0, 0);
        acc3 = __builtin_amdgcn_mfma_f32_16x16x32_bf16(a, b3, acc3, 0, 0, 0);
    }
    int rbase = (lane >> 4) * 4, col = lane & 15;
    #pragma unroll
    for (int r = 0; r < 4; r++) {
        int row = m_base + rbase + r;
        fp[(size_t)row * HID + n_base + 0 + col]  = f2b(acc0[r]);
        fp[(size_t)row * HID + n_base + 16 + col] = f2b(acc1[r]);
        fp[(size_t)row * HID + n_base + 32 + col] = f2b(acc2[r]);
        fp[(size_t)row * HID + n_base + 48 + col] = f2b(acc3[r]);
    }
}

__global__ __launch_bounds__(256) void fp_kernel(const void* feats, const void* i2h_w,
                                                 u16* fp, const int* flagp) {
    if (*flagp) fp_body((const u16*)feats, (const u16*)i2h_w, fp);
    else        fp_body((const float*)feats, (const float*)i2h_w, fp);
}

// ---------------- ROI-align 2x2 (one output element per thread)
template <typename T>
__device__ __forceinline__ void do_crop(
    const T* __restrict__ f, int C, int H, int W,
    float x1, float y1, float x2, float y2,
    u16* __restrict__ xrow, int off, int tid)
{
    int n = C * 4;
    if (tid >= n) return;
    float bw = fmaxf(x2 - x1, 1.f) * 0.5f;
    float bh = fmaxf(y2 - y1, 1.f) * 0.5f;
    int c = tid >> 2, iy = (tid >> 1) & 1, ix = tid & 1;
    float yy = y1 + (0.5f + (float)iy) * bh;
    float xx = x1 + (0.5f + (float)ix) * bw;
    bool valid = (yy >= -1.f) && (yy <= (float)H) && (xx >= -1.f) && (xx <= (float)W);
    float y = fminf(fmaxf(yy, 0.f), (float)(H - 1));
    float x = fminf(fmaxf(xx, 0.f), (float)(W - 1));
    float y0f = floorf(y), x0f = floorf(x);
    int y0 = (int)y0f, x0 = (int)x0f;
    int y1i = min(y0 + 1, H - 1), x1i = min(x0 + 1, W - 1);
    float ly = y - y0f, lx = x - x0f, hy = 1.f - ly, hx = 1.f - lx;
    size_t base = (size_t)c * H * W;
    float v = ldf(f, base + y0 * W + x0) * hy * hx + ldf(f, base + y0 * W + x1i) * hy * lx
            + ldf(f, base + y1i * W + x0) * ly * hx + ldf(f, base + y1i * W + x1i) * ly * lx;
    xrow[off + tid] = f2b(valid ? v : 0.f);
}

// ---------------- attention step: one block per batch element
template <typename T>
__device__ void attn_body(
    const T* feats, const T* pose,
    const T* pyr0, const T* pyr1, const T* pyr2,
    const int* text,
    const T* h2h_w, const T* h2h_b, const T* score_w,
    const T* pose_w, const T* pose_b, const T* char_emb,
    const u16* fp, const u16* h_prev, u16* xout, int s)
{
    const int b = blockIdx.x;
    const int tid = threadIdx.x;
    extern __shared__ float smem[];
    float* h_s = smem;            // 256
    float* sw_s = smem + 256;     // 256
    float* hp_s = smem + 512;     // 256
    float* ep_s = smem + 768;     // 256
    float* e_s = smem + 1024;     // 128
    float* ctx_s = smem + 1152;   // 768
    float* coord_s = smem + 1920; // 4
    float* red_s = smem + 1924;   // 2   -> total 1926 floats = 7704 B

    h_s[tid] = b2f(h_prev[b * HID + tid]);
    sw_s[tid] = ldf(score_w, tid);
    __syncthreads();

    // hp[j] = h . h2h_w[j,:] + h2h_b[j]
    {
        float acc = ldf(h2h_b, tid);
        const T* wr = h2h_w + (size_t)tid * HID;
        #pragma unroll 4
        for (int k4 = 0; k4 < HID / 4; k4++) {
            float4 wv = ld4(wr + 4 * k4);
            acc += h_s[4 * k4 + 0] * wv.x + h_s[4 * k4 + 1] * wv.y
                 + h_s[4 * k4 + 2] * wv.z + h_s[4 * k4 + 3] * wv.w;
        }
        hp_s[tid] = acc;
    }
    __syncthreads();

    // e[t] = sum_h tanh(fp[t,b,h] + hp[h]) * score_w[h]   (2 threads per t)
    {
        int t = tid >> 1, hf = tid & 1;
        const ushort4* fr = (const ushort4*)(fp + ((size_t)t * NB + b) * HID + hf * 128);
        float acc = 0.f;
        for (int k4 = 0; k4 < 32; k4++) {
            ushort4 v = fr[k4];
            int k = hf * 128 + 4 * k4;
            acc += tanhf(b2f(v.x) + hp_s[k + 0]) * sw_s[k + 0];
            acc += tanhf(b2f(v.y) + hp_s[k + 1]) * sw_s[k + 1];
            acc += tanhf(b2f(v.z) + hp_s[k + 2]) * sw_s[k + 2];
            acc += tanhf(b2f(v.w) + hp_s[k + 3]) * sw_s[k + 3];
        }
        ep_s[tid] = acc;
    }
    __syncthreads();
    if (tid < NT) e_s[tid] = ep_s[2 * tid] + ep_s[2 * tid + 1];
    __syncthreads();

    // softmax over t
    if (tid < 64) {
        float m = fmaxf(e_s[tid], e_s[tid + 64]);
        for (int off = 32; off; off >>= 1) m = fmaxf(m, __shfl_down(m, off));
        if (tid == 0) red_s[0] = m;
    }
    __syncthreads();
    float mx = red_s[0];
    if (tid < NT) e_s[tid] = expf(e_s[tid] - mx);
    __syncthreads();
    if (tid < 64) {
        float sm = e_s[tid] + e_s[tid + 64];
        for (int off = 32; off; off >>= 1) sm += __shfl_down(sm, off);
        if (tid == 0) red_s[1] = sm;
    }
    __syncthreads();
    float inv = 1.f / red_s[1];
    if (tid < NT) e_s[tid] *= inv;  // alpha
    __syncthreads();

    u16* xr = xout + (size_t)b * RNN_IN;

    // ctx = sum_t alpha[t] * feats_cat[t,b,:]
    for (int c = tid; c < NC; c += 256) {
        float acc = 0.f;
        size_t base = (size_t)b * NC + c;
        #pragma unroll 4
        for (int t = 0; t < NT; t++) acc += e_s[t] * ldf(feats, base + (size_t)t * NB * NC);
        ctx_s[c] = acc;
        xr[c] = f2b(acc);
    }
    {
        const T* pr = pose + (size_t)b * POSEC * NT + (size_t)tid * NT;
        float acc = 0.f;
        for (int t4 = 0; t4 < NT / 4; t4++) {
            float4 v = ld4(pr + 4 * t4);
            acc += e_s[4 * t4 + 0] * v.x + e_s[4 * t4 + 1] * v.y
                 + e_s[4 * t4 + 2] * v.z + e_s[4 * t4 + 3] * v.w;
        }
        ctx_s[NC + tid] = acc;
        xr[NC + tid] = f2b(acc);
    }
    __syncthreads();

    // coord = sigmoid(ctx @ pose_w.T + pose_b)  (one wave per output)
    {
        int j = tid >> 6, lane = tid & 63;
        float acc = 0.f;
        for (int c = lane; c < 768; c += 64) acc += ctx_s[c] * ldf(pose_w, (size_t)j * 768 + c);
        for (int off = 32; off; off >>= 1) acc += __shfl_down(acc, off);
        if (lane == 0) coord_s[j] = sigm(acc + ldf(pose_b, j));
    }
    __syncthreads();

    float c0 = coord_s[0], c1 = coord_s[1], c2 = coord_s[2], c3 = coord_s[3];
    // cumulative scales: L0 (16,128); L1 *(8,64); L2 *(4,65)
    do_crop(pyr0, 16, 16, 128, c0 * 16.f,  c1 * 128.f,    c2 * 16.f,  c3 * 128.f,    xr, 896,  tid);
    do_crop(pyr1, 64, 8,  64,  c0 * 128.f, c1 * 8192.f,   c2 * 128.f, c3 * 8192.f,   xr, 960,  tid);
    do_crop(pyr2, 64, 4,  65,  c0 * 512.f, c1 * 532480.f, c2 * 512.f, c3 * 532480.f, xr, 1216, tid);

    // embedding
    if (tid < EMB) {
        int tgt = (s > 0) ? (text[b * NSTEPS + (s - 1)] + 1) : 0;
        xr[768 + tid] = f2b(ldf(char_emb, (size_t)tgt * EMB + tid));
    }
}

__global__ __launch_bounds__(256) void attn_kernel(
    const void* feats, const void* pose,
    const void* pyr0, const void* pyr1, const void* pyr2,
    const int* text,
    const void* h2h_w, const void* h2h_b, const void* score_w,
    const void* pose_w, const void* pose_b, const void* char_emb,
    const u16* fp, const u16* h_prev, u16* xout, int s, const int* flagp)
{
    if (*flagp)
        attn_body((const u16*)feats, (const u16*)pose, (const u16*)pyr0, (const u16*)pyr1,
                  (const u16*)pyr2, text, (const u16*)h2h_w, (const u16*)h2h_b,
                  (const u16*)score_w, (const u16*)pose_w, (const u16*)pose_b,
                  (const u16*)char_emb, fp, h_prev, xout, s);
    else
        attn_body((const float*)feats, (const float*)pose, (const float*)pyr0, (const float*)pyr1,
                  (const float*)pyr2, text, (const float*)h2h_w, (const float*)h2h_b,
                  (const float*)score_w, (const float*)pose_w, (const float*)pose_b,
                  (const float*)char_emb, fp, h_prev, xout, s);
}

// ---------------- GRU step: grid (16 j-tiles, 16 b-tiles), 4 waves split K
template <typename T>
__device__ void gru_body(
    const u16* x, const u16* h_prev, u16* h_new,
    const u16* w_ih, const u16* w_hh, const T* b_ih, const T* b_hh)
{
    const int jt = blockIdx.x, bt = blockIdx.y;
    const int tid = threadIdx.x;
    const int w = tid >> 6, lane = tid & 63;
    const int lr = lane & 15;
    const int kq = (lane >> 4) * 8;
    const int arow = bt * 16 + lr;

    floatx4 z4 = {0.f, 0.f, 0.f, 0.f};
    floatx4 di[3] = {z4, z4, z4}, dh[3] = {z4, z4, z4};

    for (int kc = w; kc < RNN_IN / 32; kc += 4) {
        int k0 = kc * 32 + kq;
        short8 a = *(const short8*)(x + (size_t)arow * RNN_IN + k0);
        #pragma unroll
        for (int g = 0; g < 3; g++) {
            short8 bf = *(const short8*)(w_ih + (size_t)(g * HID + jt * 16 + lr) * RNN_IN + k0);
            di[g] = __builtin_amdgcn_mfma_f32_16x16x32_bf16(a, bf, di[g], 0, 0, 0);
        }
    }
    for (int kc = w; kc < HID / 32; kc += 4) {
        int k0 = kc * 32 + kq;
        short8 a = *(const short8*)(h_prev + (size_t)arow * HID + k0);
        #pragma unroll
        for (int g = 0; g < 3; g++) {
            short8 bf = *(const short8*)(w_hh + (size_t)(g * HID + jt * 16 + lr) * HID + k0);
            dh[g] = __builtin_amdgcn_mfma_f32_16x16x32_bf16(a, bf, dh[g], 0, 0, 0);
        }
    }

    extern __shared__ float red[];  // [4][6][16][17]
    int jcol = lane & 15, rb = (lane >> 4) * 4;
    #pragma unroll
    for (int g = 0; g < 3; g++)
        #pragma unroll
        for (int r = 0; r < 4; r++) {
            red[((w * 6 + g) * 16 + jcol) * 17 + rb + r] = di[g][r];
            red[((w * 6 + 3 + g) * 16 + jcol) * 17 + rb + r] = dh[g][r];
        }
    __syncthreads();

    int jj = tid >> 4, bl = tid & 15;
    float ir = 0, iz = 0, in = 0, hr = 0, hz = 0, hn = 0;
    #pragma unroll
    for (int w2 = 0; w2 < 4; w2++) {
        ir += red[((w2 * 6 + 0) * 16 + jj) * 17 + bl];
        iz += red[((w2 * 6 + 1) * 16 + jj) * 17 + bl];
        in += red[((w2 * 6 + 2) * 16 + jj) * 17 + bl];
        hr += red[((w2 * 6 + 3) * 16 + jj) * 17 + bl];
        hz += red[((w2 * 6 + 4) * 16 + jj) * 17 + bl];
        hn += red[((w2 * 6 + 5) * 16 + jj) * 17 + bl];
    }
    int j = jt * 16 + jj, b = bt * 16 + bl;
    ir += ldf(b_ih, j);       hr += ldf(b_hh, j);
    iz += ldf(b_ih, j + 256); hz += ldf(b_hh, j + 256);
    in += ldf(b_ih, j + 512); hn += ldf(b_hh, j + 512);
    float r = sigm(ir + hr);
    float zz = sigm(iz + hz);
    float n = tanhf(in + r * hn);
    float hp = b2f(h_prev[(size_t)b * HID + j]);
    h_new[(size_t)b * HID + j] = f2b((1.f - zz) * n + zz * hp);
}

__global__ __launch_bounds__(256) void gru_kernel(
    const u16* x, const u16* h_prev, u16* h_new,
    const u16* w_ih, const u16* w_hh,
    const void* b_ih, const void* b_hh, const int* flagp)
{
    if (*flagp) gru_body(x, h_prev, h_new, w_ih, w_hh, (const u16*)b_ih, (const u16*)b_hh);
    else        gru_body(x, h_prev, h_new, w_ih, w_hh, (const float*)b_ih, (const float*)b_hh);
}

// ---------------- final classifier
template <typename T>
__device__ void gen_body(const u16* hs, const T* gen_w, const T* gen_b, void* out) {
    int rowid = blockIdx.x;
    int b = rowid / NSTEPS, s = rowid % NSTEPS;
    const u16* h = hs + ((size_t)(s + 1) * NB + b) * HID;
    extern __shared__ float hsd[];
    int tid = threadIdx.x;
    for (int i = tid; i < HID; i += 64) hsd[i] = b2f(h[i]);
    __syncthreads();
    if (tid < NCLS) {
        float acc = ldf(gen_b, tid);
        const T* wr = gen_w + (size_t)tid * HID;
        #pragma unroll 4
        for (int k4 = 0; k4 < HID / 4; k4++) {
            float4 wv = ld4(wr + 4 * k4);
            acc += hsd[4 * k4 + 0] * wv.x + hsd[4 * k4 + 1] * wv.y
                 + hsd[4 * k4 + 2] * wv.z + hsd[4 * k4 + 3] * wv.w;
        }
        size_t o = (size_t)rowid * NCLS + tid;
        if (sizeof(T) == 2) ((u16*)out)[o] = f2b(acc);
        else                ((float*)out)[o] = acc;
    }
}

__global__ __launch_bounds__(64) void gen_kernel(
    const u16* hs, const void* gen_w, const void* gen_b, void* out, const int* flagp)
{
    if (*flagp) gen_body(hs, (const u16*)gen_w, (const u16*)gen_b, out);
    else        gen_body(hs, (const float*)gen_w, (const float*)gen_b, out);
}

extern "C" void kernel_launch(void* const* d_in, const int* in_sizes, int n_in,
                              void* d_out, int out_size, void* d_ws, size_t ws_size,
                              hipStream_t stream) {
    (void)in_sizes; (void)n_in; (void)out_size; (void)ws_size;
    const int* text = (const int*)d_in[6];

    char* ws = (char*)d_ws;
    int* flag  = (int*)ws;                    // 256 B slot
    u16* fp    = (u16*)(ws + 256);            // 16,777,216 B
    u16* hs    = (u16*)(ws + 16777472);       //  3,407,872 B
    u16* x     = (u16*)(ws + 20185344);       //    753,664 B
    u16* wih_c = (u16*)(ws + 20939008);       //  2,260,992 B
    u16* whh_c = (u16*)(ws + 23200000);       //    393,216 B  (end 23,593,216)

    probe_kernel<<<1, 128, 0, stream>>>(d_in[10], flag);
    conv_kernel<<<512, 256, 0, stream>>>(d_in[13], d_in[14], wih_c, whh_c, flag);
    hipMemsetAsync(hs, 0, (size_t)NB * HID * 2, stream);  // h0 = 0
    fp_kernel<<<dim3(512, 4), 256, 0, stream>>>(d_in[0], d_in[7], fp, flag);

    for (int s = 0; s < NSTEPS; s++) {
        attn_kernel<<<NB, 256, 7704, stream>>>(
            d_in[0], d_in[1], d_in[2], d_in[3], d_in[4], text,
            d_in[8], d_in[9], d_in[10], d_in[11], d_in[12], d_in[17],
            fp, hs + (size_t)s * NB * HID, x, s, flag);
        gru_kernel<<<dim3(16, 16), 256, 26112, stream>>>(
            x, hs + (size_t)s * NB * HID, hs + (size_t)(s + 1) * NB * HID,
            wih_c, whh_c, d_in[15], d_in[16], flag);
    }
    gen_kernel<<<NB * NSTEPS, 64, 1024, stream>>>(hs, d_in[18], d_in[19], d_out, flag);
}

// Round 3
// 1714.726 us; speedup vs baseline: 1.1848x; 1.1848x over previous
//
#include <hip/hip_runtime.h>
#include <hip/hip_bf16.h>

typedef unsigned short u16;
typedef unsigned int u32;
typedef __attribute__((ext_vector_type(8))) short short8;
typedef __attribute__((ext_vector_type(4))) float floatx4;

#define NT 128
#define NB 256
#define NC 512
#define HID 256
#define EMB 128
#define NCLS 37
#define NSTEPS 25
#define POSEC 256
#define RNN_IN 1472

__device__ __forceinline__ float b2f(u16 u) {
    union { float f; u32 i; } v; v.i = ((u32)u) << 16; return v.f;
}
__device__ __forceinline__ u16 f2b(float f) {
    union { float f; u32 i; } v; v.f = f;
    u32 x = v.i;
    return (u16)((x + 0x7fffu + ((x >> 16) & 1u)) >> 16);  // RNE
}
__device__ __forceinline__ float sigm(float x) { return 1.f / (1.f + expf(-x)); }

// dtype-polymorphic loads
__device__ __forceinline__ float ldf(const float* p, size_t i) { return p[i]; }
__device__ __forceinline__ float ldf(const u16* p, size_t i) { return b2f(p[i]); }

__device__ __forceinline__ short8 ld8(const u16* p) { return *(const short8*)p; }
__device__ __forceinline__ short8 ld8(const float* p) {
    float4 a = *(const float4*)p; float4 b = *(const float4*)(p + 4);
    short8 r;
    r[0] = (short)f2b(a.x); r[1] = (short)f2b(a.y); r[2] = (short)f2b(a.z); r[3] = (short)f2b(a.w);
    r[4] = (short)f2b(b.x); r[5] = (short)f2b(b.y); r[6] = (short)f2b(b.z); r[7] = (short)f2b(b.w);
    return r;
}
__device__ __forceinline__ float4 ld4(const float* p) { return *(const float4*)p; }
__device__ __forceinline__ float4 ld4(const u16* p) {
    ushort4 v = *(const ushort4*)p;
    return make_float4(b2f(v.x), b2f(v.y), b2f(v.z), b2f(v.w));
}

// ---------------- dtype probe (1 = bf16, 0 = f32)
__global__ void probe_kernel(const void* score_w, int* flag) {
    __shared__ float red[128];
    int tid = threadIdx.x;
    const u16* p = (const u16*)score_w;
    float v = fabsf(b2f(p[tid]));
    v = (v == v && v < 1e6f) ? v : 1e6f;
    red[tid] = v;
    __syncthreads();
    for (int s2 = 64; s2 > 0; s2 >>= 1) {
        if (tid < s2) red[tid] += red[tid + s2];
        __syncthreads();
    }
    if (tid == 0) flag[0] = (red[0] < 1000.f) ? 1 : 0;
}

// ---------------- canonicalize GRU weights to bf16 + pack h2h_w transposed
// h2h_wT packed: out[(c>>1)*512 + 2*j + (c&1)] = h2h_w[j][c]
__global__ void conv_kernel(const void* w_ih, const void* w_hh, const void* h2h_w,
                            u16* out_ih, u16* out_hh, u16* out_h2h, const int* flagp) {
    int f = *flagp;
    int idx = blockIdx.x * blockDim.x + threadIdx.x;
    int stride = gridDim.x * blockDim.x;
    const int n_ih = 768 * RNN_IN, n_hh = 768 * HID, n_h2h = HID * HID;
    if (f) {
        const u16* a = (const u16*)w_ih; const u16* b = (const u16*)w_hh;
        const u16* c = (const u16*)h2h_w;
        for (int i = idx; i < n_ih; i += stride) out_ih[i] = a[i];
        for (int i = idx; i < n_hh; i += stride) out_hh[i] = b[i];
        for (int i = idx; i < n_h2h; i += stride) {
            int j = i >> 8, cc = i & 255;
            out_h2h[(cc >> 1) * 512 + (j << 1) + (cc & 1)] = c[i];
        }
    } else {
        const float* a = (const float*)w_ih; const float* b = (const float*)w_hh;
        const float* c = (const float*)h2h_w;
        for (int i = idx; i < n_ih; i += stride) out_ih[i] = f2b(a[i]);
        for (int i = idx; i < n_hh; i += stride) out_hh[i] = f2b(b[i]);
        for (int i = idx; i < n_h2h; i += stride) {
            int j = i >> 8, cc = i & 255;
            out_h2h[(cc >> 1) * 512 + (j << 1) + (cc & 1)] = f2b(c[i]);
        }
    }
}

// ---------------- transpose feats (t,b,c) -> ft[b][c][t]
template <typename T>
__device__ void trans_body(const T* feats, u16* ft) {
    int b = blockIdx.x, t0 = blockIdx.y * 8;
    #pragma unroll
    for (int half = 0; half < 2; half++) {
        int c = threadIdx.x + half * 256;
        short8 v;
        #pragma unroll
        for (int j = 0; j < 8; j++)
            v[j] = (short)f2b(ldf(feats, ((size_t)(t0 + j) * NB + b) * NC + c));
        *(short8*)(ft + ((size_t)b * NC + c) * NT + t0) = v;
    }
}
__global__ __launch_bounds__(256) void trans_kernel(const void* feats, u16* ft, const int* flagp) {
    if (*flagp) trans_body((const u16*)feats, ft);
    else        trans_body((const float*)feats, ft);
}

// ---------------- feats_proj: fp_t[b][t][h]; A read once, full N per block
template <typename T>
__device__ void fp_body(const T* feats, const T* i2h_w, u16* fp) {
    int wave = threadIdx.x >> 6, lane = threadIdx.x & 63;
    int m_base = blockIdx.x * 64 + wave * 16;
    int lr = lane & 15;
    int kq = (lane >> 4) * 8;
    floatx4 acc[16];
    #pragma unroll
    for (int i = 0; i < 16; i++) acc[i] = (floatx4){0.f, 0.f, 0.f, 0.f};
    const int mrow = m_base + lr;
    for (int kk = 0; kk < NC; kk += 32) {
        short8 a = ld8(feats + (size_t)mrow * NC + kk + kq);
        #pragma unroll
        for (int nt = 0; nt < 16; nt++) {
            short8 bf = ld8(i2h_w + (size_t)(nt * 16 + lr) * NC + kk + kq);
            acc[nt] = __builtin_amdgcn_mfma_f32_16x16x32_bf16(a, bf, acc[nt], 0, 0, 0);
        }
    }
    int rbase = (lane >> 4) * 4, col = lane & 15;
    #pragma unroll
    for (int nt = 0; nt < 16; nt++)
        #pragma unroll
        for (int r = 0; r < 4; r++) {
            int m = m_base + rbase + r;
            int t = m >> 8, b = m & 255;
            fp[((size_t)b * NT + t) * HID + nt * 16 + col] = f2b(acc[nt][r]);
        }
}
__global__ __launch_bounds__(256) void fp_kernel(const void* feats, const void* i2h_w,
                                                 u16* fp, const int* flagp) {
    if (*flagp) fp_body((const u16*)feats, (const u16*)i2h_w, fp);
    else        fp_body((const float*)feats, (const float*)i2h_w, fp);
}

// ---------------- ROI-align 2x2
template <typename T>
__device__ __forceinline__ void do_crop(
    const T* __restrict__ f, int C, int H, int W,
    float x1, float y1, float x2, float y2,
    u16* __restrict__ xrow, int off, int tid)
{
    int n = C * 4;
    if (tid >= n) return;
    float bw = fmaxf(x2 - x1, 1.f) * 0.5f;
    float bh = fmaxf(y2 - y1, 1.f) * 0.5f;
    int c = tid >> 2, iy = (tid >> 1) & 1, ix = tid & 1;
    float yy = y1 + (0.5f + (float)iy) * bh;
    float xx = x1 + (0.5f + (float)ix) * bw;
    bool valid = (yy >= -1.f) && (yy <= (float)H) && (xx >= -1.f) && (xx <= (float)W);
    float y = fminf(fmaxf(yy, 0.f), (float)(H - 1));
    float x = fminf(fmaxf(xx, 0.f), (float)(W - 1));
    float y0f = floorf(y), x0f = floorf(x);
    int y0 = (int)y0f, x0 = (int)x0f;
    int y1i = min(y0 + 1, H - 1), x1i = min(x0 + 1, W - 1);
    float ly = y - y0f, lx = x - x0f, hy = 1.f - ly, hx = 1.f - lx;
    size_t base = (size_t)c * H * W;
    float v = ldf(f, base + y0 * W + x0) * hy * hx + ldf(f, base + y0 * W + x1i) * hy * lx
            + ldf(f, base + y1i * W + x0) * ly * hx + ldf(f, base + y1i * W + x1i) * ly * lx;
    xrow[off + tid] = f2b(valid ? v : 0.f);
}

// ---------------- attention step: one block per batch element
template <typename T>
__device__ void attn_body(
    const T* feats, const T* pose,
    const T* pyr0, const T* pyr1, const T* pyr2,
    const int* text,
    const T* h2h_b, const T* score_w,
    const T* pose_w, const T* pose_b, const T* char_emb,
    const u16* h2h_wT, const u16* ft, const u16* fp,
    const u16* h_prev, u16* xout, int s, int use_ft)
{
    const int b = blockIdx.x;
    const int tid = threadIdx.x;
    extern __shared__ float smem[];
    float* h_s = smem;            // 256
    float* sw_s = smem + 256;     // 256
    float* hp_s = smem + 512;     // 256
    float* ep_s = smem + 768;     // 256
    float* e_s = smem + 1024;     // 128
    float* ctx_s = smem + 1152;   // 768
    float* coord_s = smem + 1920; // 4
    float* red_s = smem + 1924;   // 2

    h_s[tid] = b2f(h_prev[b * HID + tid]);
    sw_s[tid] = ldf(score_w, tid);
    __syncthreads();

    // hp[j] = h . h2h_w[j,:] + h2h_b[j]  via packed-transposed weights
    {
        float acc = ldf(h2h_b, tid);
        const u16* wp = h2h_wT + 2 * tid;
        #pragma unroll 8
        for (int c2 = 0; c2 < 128; c2++) {
            u32 w2 = *(const u32*)(wp + c2 * 512);
            acc += h_s[2 * c2] * b2f((u16)w2) + h_s[2 * c2 + 1] * b2f((u16)(w2 >> 16));
        }
        hp_s[tid] = acc;
    }
    __syncthreads();

    // e[t] = sum_h tanh(fp[b][t][h] + hp[h]) * score_w[h]   (2 threads per t)
    {
        int t = tid >> 1, hf = tid & 1;
        const ushort4* fr = (const ushort4*)(fp + ((size_t)b * NT + t) * HID + hf * 128);
        float acc = 0.f;
        for (int k4 = 0; k4 < 32; k4++) {
            ushort4 v = fr[k4];
            int k = hf * 128 + 4 * k4;
            acc += tanhf(b2f(v.x) + hp_s[k + 0]) * sw_s[k + 0];
            acc += tanhf(b2f(v.y) + hp_s[k + 1]) * sw_s[k + 1];
            acc += tanhf(b2f(v.z) + hp_s[k + 2]) * sw_s[k + 2];
            acc += tanhf(b2f(v.w) + hp_s[k + 3]) * sw_s[k + 3];
        }
        ep_s[tid] = acc;
    }
    __syncthreads();
    if (tid < NT) e_s[tid] = ep_s[2 * tid] + ep_s[2 * tid + 1];
    __syncthreads();

    // softmax over t
    if (tid < 64) {
        float m = fmaxf(e_s[tid], e_s[tid + 64]);
        for (int off = 32; off; off >>= 1) m = fmaxf(m, __shfl_down(m, off));
        if (tid == 0) red_s[0] = m;
    }
    __syncthreads();
    float mx = red_s[0];
    if (tid < NT) e_s[tid] = expf(e_s[tid] - mx);
    __syncthreads();
    if (tid < 64) {
        float sm = e_s[tid] + e_s[tid + 64];
        for (int off = 32; off; off >>= 1) sm += __shfl_down(sm, off);
        if (tid == 0) red_s[1] = sm;
    }
    __syncthreads();
    float inv = 1.f / red_s[1];
    if (tid < NT) e_s[tid] *= inv;  // alpha
    __syncthreads();

    u16* xr = xout + (size_t)b * RNN_IN;

    // ctx = sum_t alpha[t] * feats_cat[t,b,:]
    if (use_ft) {
        #pragma unroll
        for (int half = 0; half < 2; half++) {
            int c = tid + half * 256;
            const u16* row = ft + ((size_t)b * NC + c) * NT;
            float acc = 0.f;
            #pragma unroll
            for (int t8 = 0; t8 < NT / 8; t8++) {
                short8 v = *(const short8*)(row + 8 * t8);
                #pragma unroll
                for (int j = 0; j < 8; j++)
                    acc += e_s[8 * t8 + j] * b2f((u16)v[j]);
            }
            ctx_s[c] = acc;
            xr[c] = f2b(acc);
        }
    } else {
        for (int c = tid; c < NC; c += 256) {
            float acc = 0.f;
            size_t base = (size_t)b * NC + c;
            #pragma unroll 4
            for (int t = 0; t < NT; t++) acc += e_s[t] * ldf(feats, base + (size_t)t * NB * NC);
            ctx_s[c] = acc;
            xr[c] = f2b(acc);
        }
    }
    {
        const T* pr = pose + (size_t)b * POSEC * NT + (size_t)tid * NT;
        float acc = 0.f;
        for (int t4 = 0; t4 < NT / 4; t4++) {
            float4 v = ld4(pr + 4 * t4);
            acc += e_s[4 * t4 + 0] * v.x + e_s[4 * t4 + 1] * v.y
                 + e_s[4 * t4 + 2] * v.z + e_s[4 * t4 + 3] * v.w;
        }
        ctx_s[NC + tid] = acc;
        xr[NC + tid] = f2b(acc);
    }
    __syncthreads();

    // coord = sigmoid(ctx @ pose_w.T + pose_b)
    {
        int j = tid >> 6, lane = tid & 63;
        float acc = 0.f;
        for (int c = lane; c < 768; c += 64) acc += ctx_s[c] * ldf(pose_w, (size_t)j * 768 + c);
        for (int off = 32; off; off >>= 1) acc += __shfl_down(acc, off);
        if (lane == 0) coord_s[j] = sigm(acc + ldf(pose_b, j));
    }
    __syncthreads();

    float c0 = coord_s[0], c1 = coord_s[1], c2 = coord_s[2], c3 = coord_s[3];
    do_crop(pyr0, 16, 16, 128, c0 * 16.f,  c1 * 128.f,    c2 * 16.f,  c3 * 128.f,    xr, 896,  tid);
    do_crop(pyr1, 64, 8,  64,  c0 * 128.f, c1 * 8192.f,   c2 * 128.f, c3 * 8192.f,   xr, 960,  tid);
    do_crop(pyr2, 64, 4,  65,  c0 * 512.f, c1 * 532480.f, c2 * 512.f, c3 * 532480.f, xr, 1216, tid);

    if (tid < EMB) {
        int tgt = (s > 0) ? (text[b * NSTEPS + (s - 1)] + 1) : 0;
        xr[768 + tid] = f2b(ldf(char_emb, (size_t)tgt * EMB + tid));
    }
}

__global__ __launch_bounds__(256) void attn_kernel(
    const void* feats, const void* pose,
    const void* pyr0, const void* pyr1, const void* pyr2,
    const int* text,
    const void* h2h_b, const void* score_w,
    const void* pose_w, const void* pose_b, const void* char_emb,
    const u16* h2h_wT, const u16* ft, const u16* fp,
    const u16* h_prev, u16* xout, int s, int use_ft, const int* flagp)
{
    if (*flagp)
        attn_body((const u16*)feats, (const u16*)pose, (const u16*)pyr0, (const u16*)pyr1,
                  (const u16*)pyr2, text, (const u16*)h2h_b, (const u16*)score_w,
                  (const u16*)pose_w, (const u16*)pose_b, (const u16*)char_emb,
                  h2h_wT, ft, fp, h_prev, xout, s, use_ft);
    else
        attn_body((const float*)feats, (const float*)pose, (const float*)pyr0, (const float*)pyr1,
                  (const float*)pyr2, text, (const float*)h2h_b, (const float*)score_w,
                  (const float*)pose_w, (const float*)pose_b, (const float*)char_emb,
                  h2h_wT, ft, fp, h_prev, xout, s, use_ft);
}

// ---------------- GRU step: grid (16 jt, 16 bt), 8 waves split K
template <typename T>
__device__ void gru_body(
    const u16* x, const u16* h_prev, u16* h_new,
    const u16* w_ih, const u16* w_hh, const T* b_ih, const T* b_hh)
{
    const int jt = blockIdx.x, bt = blockIdx.y;
    const int tid = threadIdx.x;
    const int w = tid >> 6, lane = tid & 63;
    const int lr = lane & 15;
    const int kq = (lane >> 4) * 8;
    const int arow = bt * 16 + lr;

    floatx4 z4 = {0.f, 0.f, 0.f, 0.f};
    floatx4 di[3] = {z4, z4, z4}, dh[3] = {z4, z4, z4};

    for (int kc = w; kc < RNN_IN / 32; kc += 8) {
        int k0 = kc * 32 + kq;
        short8 a = *(const short8*)(x + (size_t)arow * RNN_IN + k0);
        #pragma unroll
        for (int g = 0; g < 3; g++) {
            short8 bf = *(const short8*)(w_ih + (size_t)(g * HID + jt * 16 + lr) * RNN_IN + k0);
            di[g] = __builtin_amdgcn_mfma_f32_16x16x32_bf16(a, bf, di[g], 0, 0, 0);
        }
    }
    for (int kc = w; kc < HID / 32; kc += 8) {
        int k0 = kc * 32 + kq;
        short8 a = *(const short8*)(h_prev + (size_t)arow * HID + k0);
        #pragma unroll
        for (int g = 0; g < 3; g++) {
            short8 bf = *(const short8*)(w_hh + (size_t)(g * HID + jt * 16 + lr) * HID + k0);
            dh[g] = __builtin_amdgcn_mfma_f32_16x16x32_bf16(a, bf, dh[g], 0, 0, 0);
        }
    }

    extern __shared__ float red[];  // [8][6][16][17]
    int jcol = lane & 15, rb = (lane >> 4) * 4;
    #pragma unroll
    for (int g = 0; g < 3; g++)
        #pragma unroll
        for (int r = 0; r < 4; r++) {
            red[((w * 6 + g) * 16 + jcol) * 17 + rb + r] = di[g][r];
            red[((w * 6 + 3 + g) * 16 + jcol) * 17 + rb + r] = dh[g][r];
        }
    __syncthreads();

    if (tid < 256) {
        int jj = tid >> 4, bl = tid & 15;
        float ir = 0, iz = 0, in = 0, hr = 0, hz = 0, hn = 0;
        #pragma unroll
        for (int w2 = 0; w2 < 8; w2++) {
            ir += red[((w2 * 6 + 0) * 16 + jj) * 17 + bl];
            iz += red[((w2 * 6 + 1) * 16 + jj) * 17 + bl];
            in += red[((w2 * 6 + 2) * 16 + jj) * 17 + bl];
            hr += red[((w2 * 6 + 3) * 16 + jj) * 17 + bl];
            hz += red[((w2 * 6 + 4) * 16 + jj) * 17 + bl];
            hn += red[((w2 * 6 + 5) * 16 + jj) * 17 + bl];
        }
        int j = jt * 16 + jj, b = bt * 16 + bl;
        ir += ldf(b_ih, j);       hr += ldf(b_hh, j);
        iz += ldf(b_ih, j + 256); hz += ldf(b_hh, j + 256);
        in += ldf(b_ih, j + 512); hn += ldf(b_hh, j + 512);
        float r = sigm(ir + hr);
        float zz = sigm(iz + hz);
        float n = tanhf(in + r * hn);
        float hp = b2f(h_prev[(size_t)b * HID + j]);
        h_new[(size_t)b * HID + j] = f2b((1.f - zz) * n + zz * hp);
    }
}

__global__ __launch_bounds__(512) void gru_kernel(
    const u16* x, const u16* h_prev, u16* h_new,
    const u16* w_ih, const u16* w_hh,
    const void* b_ih, const void* b_hh, const int* flagp)
{
    if (*flagp) gru_body(x, h_prev, h_new, w_ih, w_hh, (const u16*)b_ih, (const u16*)b_hh);
    else        gru_body(x, h_prev, h_new, w_ih, w_hh, (const float*)b_ih, (const float*)b_hh);
}

// ---------------- final classifier
template <typename T>
__device__ void gen_body(const u16* hs, const T* gen_w, const T* gen_b, void* out) {
    int rowid = blockIdx.x;
    int b = rowid / NSTEPS, s = rowid % NSTEPS;
    const u16* h = hs + ((size_t)(s + 1) * NB + b) * HID;
    extern __shared__ float hsd[];
    int tid = threadIdx.x;
    for (int i = tid; i < HID; i += 64) hsd[i] = b2f(h[i]);
    __syncthreads();
    if (tid < NCLS) {
        float acc = ldf(gen_b, tid);
        const T* wr = gen_w + (size_t)tid * HID;
        #pragma unroll 4
        for (int k4 = 0; k4 < HID / 4; k4++) {
            float4 wv = ld4(wr + 4 * k4);
            acc += hsd[4 * k4 + 0] * wv.x + hsd[4 * k4 + 1] * wv.y
                 + hsd[4 * k4 + 2] * wv.z + hsd[4 * k4 + 3] * wv.w;
        }
        size_t o = (size_t)rowid * NCLS + tid;
        if (sizeof(T) == 2) ((u16*)out)[o] = f2b(acc);
        else                ((float*)out)[o] = acc;
    }
}
__global__ __launch_bounds__(64) void gen_kernel(
    const u16* hs, const void* gen_w, const void* gen_b, void* out, const int* flagp)
{
    if (*flagp) gen_body(hs, (const u16*)gen_w, (const u16*)gen_b, out);
    else        gen_body(hs, (const float*)gen_w, (const float*)gen_b, out);
}

extern "C" void kernel_launch(void* const* d_in, const int* in_sizes, int n_in,
                              void* d_out, int out_size, void* d_ws, size_t ws_size,
                              hipStream_t stream) {
    (void)in_sizes; (void)n_in; (void)out_size;
    const int* text = (const int*)d_in[6];

    char* ws = (char*)d_ws;
    size_t off = 256;
    int* flag = (int*)ws;
    u16* fp = (u16*)(ws + off); off += (size_t)NB * NT * HID * 2;        // 16.78 MB
    u16* ft = nullptr;
    int use_ft = 0;
    size_t ft_bytes = (size_t)NB * NC * NT * 2;                          // 33.55 MB
    size_t rest = 3407872 + 753664 + 2260992 + 393216 + 131072;
    if (ws_size >= off + ft_bytes + rest) {
        ft = (u16*)(ws + off); off += ft_bytes; use_ft = 1;
    }
    u16* hs     = (u16*)(ws + off); off += 3407872;
    u16* x      = (u16*)(ws + off); off += 753664;
    u16* wih_c  = (u16*)(ws + off); off += 2260992;
    u16* whh_c  = (u16*)(ws + off); off += 393216;
    u16* h2h_wT = (u16*)(ws + off); off += 131072;

    probe_kernel<<<1, 128, 0, stream>>>(d_in[10], flag);
    conv_kernel<<<512, 256, 0, stream>>>(d_in[13], d_in[14], d_in[8],
                                         wih_c, whh_c, h2h_wT, flag);
    hipMemsetAsync(hs, 0, (size_t)NB * HID * 2, stream);  // h0 = 0
    fp_kernel<<<512, 256, 0, stream>>>(d_in[0], d_in[7], fp, flag);
    if (use_ft)
        trans_kernel<<<dim3(NB, NT / 8), 256, 0, stream>>>(d_in[0], ft, flag);

    for (int s = 0; s < NSTEPS; s++) {
        attn_kernel<<<NB, 256, 7704, stream>>>(
            d_in[0], d_in[1], d_in[2], d_in[3], d_in[4], text,
            d_in[9], d_in[10], d_in[11], d_in[12], d_in[17],
            h2h_wT, ft, fp, hs + (size_t)s * NB * HID, x, s, use_ft, flag);
        gru_kernel<<<dim3(16, 16), 512, 52224, stream>>>(
            x, hs + (size_t)s * NB * HID, hs + (size_t)(s + 1) * NB * HID,
            wih_c, whh_c, d_in[15], d_in[16], flag);
    }
    gen_kernel<<<NB * NSTEPS, 64, 1024, stream>>>(hs, d_in[18], d_in[19], d_out, flag);
}

// Round 5
// 1436.779 us; speedup vs baseline: 1.4140x; 1.1935x over previous
//
#include <hip/hip_runtime.h>
#include <hip/hip_bf16.h>

typedef unsigned short u16;
typedef unsigned int u32;
typedef __attribute__((ext_vector_type(8))) short short8;
typedef __attribute__((ext_vector_type(4))) float floatx4;

#define NT 128
#define NB 256
#define NC 512
#define HID 256
#define EMB 128
#define NCLS 37
#define NSTEPS 25
#define POSEC 256
#define RNN_IN 1472

__device__ __forceinline__ float b2f(u16 u) {
    union { float f; u32 i; } v; v.i = ((u32)u) << 16; return v.f;
}
__device__ __forceinline__ u16 f2b(float f) {
    union { float f; u32 i; } v; v.f = f;
    u32 x = v.i;
    return (u16)((x + 0x7fffu + ((x >> 16) & 1u)) >> 16);  // RNE
}
__device__ __forceinline__ float sigm(float x) { return 1.f / (1.f + expf(-x)); }

// dtype-polymorphic loads
__device__ __forceinline__ float ldf(const float* p, size_t i) { return p[i]; }
__device__ __forceinline__ float ldf(const u16* p, size_t i) { return b2f(p[i]); }

__device__ __forceinline__ short8 ld8(const u16* p) { return *(const short8*)p; }
__device__ __forceinline__ short8 ld8(const float* p) {
    float4 a = *(const float4*)p; float4 b = *(const float4*)(p + 4);
    short8 r;
    r[0] = (short)f2b(a.x); r[1] = (short)f2b(a.y); r[2] = (short)f2b(a.z); r[3] = (short)f2b(a.w);
    r[4] = (short)f2b(b.x); r[5] = (short)f2b(b.y); r[6] = (short)f2b(b.z); r[7] = (short)f2b(b.w);
    return r;
}
__device__ __forceinline__ float4 ld4(const float* p) { return *(const float4*)p; }
__device__ __forceinline__ float4 ld4(const u16* p) {
    ushort4 v = *(const ushort4*)p;
    return make_float4(b2f(v.x), b2f(v.y), b2f(v.z), b2f(v.w));
}

// ---------------- dtype probe (1 = bf16, 0 = f32)
__global__ void probe_kernel(const void* score_w, int* flag) {
    __shared__ float red[128];
    int tid = threadIdx.x;
    const u16* p = (const u16*)score_w;
    float v = fabsf(b2f(p[tid]));
    v = (v == v && v < 1e6f) ? v : 1e6f;
    red[tid] = v;
    __syncthreads();
    for (int s2 = 64; s2 > 0; s2 >>= 1) {
        if (tid < s2) red[tid] += red[tid + s2];
        __syncthreads();
    }
    if (tid == 0) flag[0] = (red[0] < 1000.f) ? 1 : 0;
}

// ---------------- canonicalize GRU weights to bf16 + pack h2h_w transposed
// h2h_wT packed: out[(c>>1)*512 + 2*j + (c&1)] = h2h_w[j][c]
__global__ void conv_kernel(const void* w_ih, const void* w_hh, const void* h2h_w,
                            u16* out_ih, u16* out_hh, u16* out_h2h, const int* flagp) {
    int f = *flagp;
    int idx = blockIdx.x * blockDim.x + threadIdx.x;
    int stride = gridDim.x * blockDim.x;
    const int n_ih = 768 * RNN_IN, n_hh = 768 * HID, n_h2h = HID * HID;
    if (f) {
        const u16* a = (const u16*)w_ih; const u16* b = (const u16*)w_hh;
        const u16* c = (const u16*)h2h_w;
        for (int i = idx; i < n_ih; i += stride) out_ih[i] = a[i];
        for (int i = idx; i < n_hh; i += stride) out_hh[i] = b[i];
        for (int i = idx; i < n_h2h; i += stride) {
            int j = i >> 8, cc = i & 255;
            out_h2h[(cc >> 1) * 512 + (j << 1) + (cc & 1)] = c[i];
        }
    } else {
        const float* a = (const float*)w_ih; const float* b = (const float*)w_hh;
        const float* c = (const float*)h2h_w;
        for (int i = idx; i < n_ih; i += stride) out_ih[i] = f2b(a[i]);
        for (int i = idx; i < n_hh; i += stride) out_hh[i] = f2b(b[i]);
        for (int i = idx; i < n_h2h; i += stride) {
            int j = i >> 8, cc = i & 255;
            out_h2h[(cc >> 1) * 512 + (j << 1) + (cc & 1)] = f2b(c[i]);
        }
    }
}

// ---------------- transpose feats (t,b,c) -> ft[b][c][t]
template <typename T>
__device__ void trans_body(const T* feats, u16* ft) {
    int b = blockIdx.x, t0 = blockIdx.y * 8;
    #pragma unroll
    for (int half = 0; half < 2; half++) {
        int c = threadIdx.x + half * 256;
        short8 v;
        #pragma unroll
        for (int j = 0; j < 8; j++)
            v[j] = (short)f2b(ldf(feats, ((size_t)(t0 + j) * NB + b) * NC + c));
        *(short8*)(ft + ((size_t)b * NC + c) * NT + t0) = v;
    }
}
__global__ __launch_bounds__(256) void trans_kernel(const void* feats, u16* ft, const int* flagp) {
    if (*flagp) trans_body((const u16*)feats, ft);
    else        trans_body((const float*)feats, ft);
}

// ---------------- feats_proj: LDS-tiled MFMA GEMM, 128x128 tile, BK=32
// M = NT*NB = 32768 (rows t*NB+b), N = 256, K = 512. fp out layout [b][t][h].
// Staging: 2 threads/row, each loads 16 halves (two short8) -> full 32-half row.
template <typename T>
__device__ void fp_body(const T* feats, const T* i2h_w, u16* fp) {
    __shared__ u16 As[128][40];   // +8 pad
    __shared__ u16 Bs[128][40];
    const int tid = threadIdx.x;
    const int w = tid >> 6, lane = tid & 63;
    const int m0 = blockIdx.x * 128, n0 = blockIdx.y * 128;
    const int lr = lane & 15, kq = (lane >> 4) * 8;
    const int srow = tid >> 1, schunk = (tid & 1) * 16;

    floatx4 acc[2][8];
    #pragma unroll
    for (int i = 0; i < 2; i++)
        #pragma unroll
        for (int nt = 0; nt < 8; nt++) acc[i][nt] = (floatx4){0.f, 0.f, 0.f, 0.f};

    for (int kk = 0; kk < NC; kk += 32) {
        short8 av0 = ld8(feats + (size_t)(m0 + srow) * NC + kk + schunk);
        short8 av1 = ld8(feats + (size_t)(m0 + srow) * NC + kk + schunk + 8);
        short8 bv0 = ld8(i2h_w + (size_t)(n0 + srow) * NC + kk + schunk);
        short8 bv1 = ld8(i2h_w + (size_t)(n0 + srow) * NC + kk + schunk + 8);
        __syncthreads();
        *(short8*)&As[srow][schunk] = av0;
        *(short8*)&As[srow][schunk + 8] = av1;
        *(short8*)&Bs[srow][schunk] = bv0;
        *(short8*)&Bs[srow][schunk + 8] = bv1;
        __syncthreads();
        short8 a0 = *(const short8*)&As[w * 32 + lr][kq];
        short8 a1 = *(const short8*)&As[w * 32 + 16 + lr][kq];
        #pragma unroll
        for (int nt = 0; nt < 8; nt++) {
            short8 bf = *(const short8*)&Bs[nt * 16 + lr][kq];
            acc[0][nt] = __builtin_amdgcn_mfma_f32_16x16x32_bf16(a0, bf, acc[0][nt], 0, 0, 0);
            acc[1][nt] = __builtin_amdgcn_mfma_f32_16x16x32_bf16(a1, bf, acc[1][nt], 0, 0, 0);
        }
    }

    int rbase = (lane >> 4) * 4, col = lane & 15;
    #pragma unroll
    for (int i = 0; i < 2; i++)
        #pragma unroll
        for (int nt = 0; nt < 8; nt++)
            #pragma unroll
            for (int r = 0; r < 4; r++) {
                int m = m0 + w * 32 + i * 16 + rbase + r;
                int t = m >> 8, b = m & 255;
                fp[((size_t)b * NT + t) * HID + n0 + nt * 16 + col] = f2b(acc[i][nt][r]);
            }
}
__global__ __launch_bounds__(256) void fp_kernel(const void* feats, const void* i2h_w,
                                                 u16* fp, const int* flagp) {
    if (*flagp) fp_body((const u16*)feats, (const u16*)i2h_w, fp);
    else        fp_body((const float*)feats, (const float*)i2h_w, fp);
}

// ---------------- ROI-align 2x2
template <typename T>
__device__ __forceinline__ void do_crop(
    const T* __restrict__ f, int C, int H, int W,
    float x1, float y1, float x2, float y2,
    u16* __restrict__ xrow, int off, int tid)
{
    int n = C * 4;
    if (tid >= n) return;
    float bw = fmaxf(x2 - x1, 1.f) * 0.5f;
    float bh = fmaxf(y2 - y1, 1.f) * 0.5f;
    int c = tid >> 2, iy = (tid >> 1) & 1, ix = tid & 1;
    float yy = y1 + (0.5f + (float)iy) * bh;
    float xx = x1 + (0.5f + (float)ix) * bw;
    bool valid = (yy >= -1.f) && (yy <= (float)H) && (xx <= (float)W) && (xx >= -1.f);
    float y = fminf(fmaxf(yy, 0.f), (float)(H - 1));
    float x = fminf(fmaxf(xx, 0.f), (float)(W - 1));
    float y0f = floorf(y), x0f = floorf(x);
    int y0 = (int)y0f, x0 = (int)x0f;
    int y1i = min(y0 + 1, H - 1), x1i = min(x0 + 1, W - 1);
    float ly = y - y0f, lx = x - x0f, hy = 1.f - ly, hx = 1.f - lx;
    size_t base = (size_t)c * H * W;
    float v = ldf(f, base + y0 * W + x0) * hy * hx + ldf(f, base + y0 * W + x1i) * hy * lx
            + ldf(f, base + y1i * W + x0) * ly * hx + ldf(f, base + y1i * W + x1i) * ly * lx;
    xrow[off + tid] = f2b(valid ? v : 0.f);
}

// ---------------- attention step: one block (512 thr) per batch element
template <typename T>
__device__ void attn_body(
    const T* pose,
    const T* pyr0, const T* pyr1, const T* pyr2,
    const int* text,
    const T* h2h_b, const T* score_w,
    const T* pose_w, const T* pose_b, const T* char_emb,
    const u16* h2h_wT, const u16* ft, const u16* fp,
    const u16* h_prev, u16* xout, int s)
{
    const int b = blockIdx.x;
    const int tid = threadIdx.x;
    extern __shared__ float smem[];
    float* h_s    = smem;          // 256
    float* sw_s   = smem + 256;    // 256
    float* hp_s   = smem + 512;    // 256
    float* ep_s   = smem + 768;    // 512
    float* e_s    = smem + 1280;   // 128
    float* ctx_s  = smem + 1408;   // 768
    float* coord_s= smem + 2176;   // 4
    float* red_s  = smem + 2180;   // 2   -> 2182 floats = 8728 B

    if (tid < 256) {
        h_s[tid] = b2f(h_prev[b * HID + tid]);
        sw_s[tid] = ldf(score_w, tid);
    }
    __syncthreads();

    // hp[j] = h . h2h_w[j,:] + h2h_b[j], 2-way K-split via packed-T weights
    {
        int j = tid & 255, half = tid >> 8;
        float acc = 0.f;
        const u16* wp = h2h_wT + 2 * j + (size_t)half * 64 * 512;
        #pragma unroll 8
        for (int c2 = 0; c2 < 64; c2++) {
            u32 w2 = *(const u32*)(wp + c2 * 512);
            acc += h_s[half * 128 + 2 * c2] * b2f((u16)w2)
                 + h_s[half * 128 + 2 * c2 + 1] * b2f((u16)(w2 >> 16));
        }
        ep_s[tid] = acc;
    }
    __syncthreads();
    if (tid < 256) hp_s[tid] = ep_s[tid] + ep_s[tid + 256] + ldf(h2h_b, tid);
    __syncthreads();

    // e[t] = sum_h tanh(fp[b][t][h] + hp[h]) * score_w[h]   (4 threads per t)
    {
        int t = tid >> 2, q = tid & 3;
        const ushort4* fr = (const ushort4*)(fp + ((size_t)b * NT + t) * HID + q * 64);
        float acc = 0.f;
        #pragma unroll
        for (int k4 = 0; k4 < 16; k4++) {
            ushort4 v = fr[k4];
            int k = q * 64 + 4 * k4;
            acc += tanhf(b2f(v.x) + hp_s[k + 0]) * sw_s[k + 0];
            acc += tanhf(b2f(v.y) + hp_s[k + 1]) * sw_s[k + 1];
            acc += tanhf(b2f(v.z) + hp_s[k + 2]) * sw_s[k + 2];
            acc += tanhf(b2f(v.w) + hp_s[k + 3]) * sw_s[k + 3];
        }
        ep_s[tid] = acc;
    }
    __syncthreads();
    if (tid < NT)
        e_s[tid] = ep_s[4 * tid] + ep_s[4 * tid + 1] + ep_s[4 * tid + 2] + ep_s[4 * tid + 3];
    __syncthreads();

    // softmax over t
    if (tid < 64) {
        float m = fmaxf(e_s[tid], e_s[tid + 64]);
        for (int off = 32; off; off >>= 1) m = fmaxf(m, __shfl_down(m, off));
        if (tid == 0) red_s[0] = m;
    }
    __syncthreads();
    float mx = red_s[0];
    if (tid < NT) e_s[tid] = expf(e_s[tid] - mx);
    __syncthreads();
    if (tid < 64) {
        float sm = e_s[tid] + e_s[tid + 64];
        for (int off = 32; off; off >>= 1) sm += __shfl_down(sm, off);
        if (tid == 0) red_s[1] = sm;
    }
    __syncthreads();
    float inv = 1.f / red_s[1];
    if (tid < NT) e_s[tid] *= inv;  // alpha
    __syncthreads();

    u16* xr = xout + (size_t)b * RNN_IN;

    // ctx feats part: one channel per thread (512 channels)
    {
        int c = tid;
        const u16* row = ft + ((size_t)b * NC + c) * NT;
        float acc = 0.f;
        #pragma unroll
        for (int t8 = 0; t8 < NT / 8; t8++) {
            short8 v = *(const short8*)(row + 8 * t8);
            #pragma unroll
            for (int j = 0; j < 8; j++)
                acc += e_s[8 * t8 + j] * b2f((u16)v[j]);
        }
        ctx_s[c] = acc;
        xr[c] = f2b(acc);
    }
    // ctx pose part (256 channels)
    if (tid < 256) {
        const T* pr = pose + (size_t)b * POSEC * NT + (size_t)tid * NT;
        float acc = 0.f;
        #pragma unroll
        for (int t4 = 0; t4 < NT / 4; t4++) {
            float4 v = ld4(pr + 4 * t4);
            acc += e_s[4 * t4 + 0] * v.x + e_s[4 * t4 + 1] * v.y
                 + e_s[4 * t4 + 2] * v.z + e_s[4 * t4 + 3] * v.w;
        }
        ctx_s[NC + tid] = acc;
        xr[NC + tid] = f2b(acc);
    }
    __syncthreads();

    // coord = sigmoid(ctx @ pose_w.T + pose_b)
    if (tid < 256) {
        int j = tid >> 6, lane = tid & 63;
        float acc = 0.f;
        for (int c = lane; c < 768; c += 64) acc += ctx_s[c] * ldf(pose_w, (size_t)j * 768 + c);
        for (int off = 32; off; off >>= 1) acc += __shfl_down(acc, off);
        if (lane == 0) coord_s[j] = sigm(acc + ldf(pose_b, j));
    }
    __syncthreads();

    float c0 = coord_s[0], c1 = coord_s[1], c2 = coord_s[2], c3 = coord_s[3];
    do_crop(pyr0, 16, 16, 128, c0 * 16.f,  c1 * 128.f,    c2 * 16.f,  c3 * 128.f,    xr, 896,  tid);
    do_crop(pyr1, 64, 8,  64,  c0 * 128.f, c1 * 8192.f,   c2 * 128.f, c3 * 8192.f,   xr, 960,  tid);
    do_crop(pyr2, 64, 4,  65,  c0 * 512.f, c1 * 532480.f, c2 * 512.f, c3 * 532480.f, xr, 1216, tid);

    if (tid < EMB) {
        int tgt = (s > 0) ? (text[b * NSTEPS + (s - 1)] + 1) : 0;
        xr[768 + tid] = f2b(ldf(char_emb, (size_t)tgt * EMB + tid));
    }
}

__global__ __launch_bounds__(512) void attn_kernel(
    const void* pose,
    const void* pyr0, const void* pyr1, const void* pyr2,
    const int* text,
    const void* h2h_b, const void* score_w,
    const void* pose_w, const void* pose_b, const void* char_emb,
    const u16* h2h_wT, const u16* ft, const u16* fp,
    const u16* h_prev, u16* xout, int s, const int* flagp)
{
    if (*flagp)
        attn_body((const u16*)pose, (const u16*)pyr0, (const u16*)pyr1,
                  (const u16*)pyr2, text, (const u16*)h2h_b, (const u16*)score_w,
                  (const u16*)pose_w, (const u16*)pose_b, (const u16*)char_emb,
                  h2h_wT, ft, fp, h_prev, xout, s);
    else
        attn_body((const float*)pose, (const float*)pyr0, (const float*)pyr1,
                  (const float*)pyr2, text, (const float*)h2h_b, (const float*)score_w,
                  (const float*)pose_w, (const float*)pose_b, (const float*)char_emb,
                  h2h_wT, ft, fp, h_prev, xout, s);
}

// ---------------- GRU step: grid (16 jt, 16 bt), 8 waves split K, fused r/z acc
template <typename T>
__device__ void gru_body(
    const u16* x, const u16* h_prev, u16* h_new,
    const u16* w_ih, const u16* w_hh, const T* b_ih, const T* b_hh)
{
    const int jt = blockIdx.x, bt = blockIdx.y;
    const int tid = threadIdx.x;
    const int w = tid >> 6, lane = tid & 63;
    const int lr = lane & 15;
    const int kq = (lane >> 4) * 8;
    const int arow = bt * 16 + lr;

    floatx4 acc_r = {0.f,0.f,0.f,0.f}, acc_z = acc_r, acc_in = acc_r, acc_hn = acc_r;

    for (int kc = w; kc < RNN_IN / 32; kc += 8) {
        int k0 = kc * 32 + kq;
        short8 a = *(const short8*)(x + (size_t)arow * RNN_IN + k0);
        short8 b0 = *(const short8*)(w_ih + (size_t)(0 * HID + jt * 16 + lr) * RNN_IN + k0);
        short8 b1 = *(const short8*)(w_ih + (size_t)(1 * HID + jt * 16 + lr) * RNN_IN + k0);
        short8 b2 = *(const short8*)(w_ih + (size_t)(2 * HID + jt * 16 + lr) * RNN_IN + k0);
        acc_r  = __builtin_amdgcn_mfma_f32_16x16x32_bf16(a, b0, acc_r, 0, 0, 0);
        acc_z  = __builtin_amdgcn_mfma_f32_16x16x32_bf16(a, b1, acc_z, 0, 0, 0);
        acc_in = __builtin_amdgcn_mfma_f32_16x16x32_bf16(a, b2, acc_in, 0, 0, 0);
    }
    for (int kc = w; kc < HID / 32; kc += 8) {
        int k0 = kc * 32 + kq;
        short8 a = *(const short8*)(h_prev + (size_t)arow * HID + k0);
        short8 b0 = *(const short8*)(w_hh + (size_t)(0 * HID + jt * 16 + lr) * HID + k0);
        short8 b1 = *(const short8*)(w_hh + (size_t)(1 * HID + jt * 16 + lr) * HID + k0);
        short8 b2 = *(const short8*)(w_hh + (size_t)(2 * HID + jt * 16 + lr) * HID + k0);
        acc_r  = __builtin_amdgcn_mfma_f32_16x16x32_bf16(a, b0, acc_r, 0, 0, 0);
        acc_z  = __builtin_amdgcn_mfma_f32_16x16x32_bf16(a, b1, acc_z, 0, 0, 0);
        acc_hn = __builtin_amdgcn_mfma_f32_16x16x32_bf16(a, b2, acc_hn, 0, 0, 0);
    }

    extern __shared__ float red[];  // [8][4][16][17]
    int jcol = lane & 15, rb = (lane >> 4) * 4;
    #pragma unroll
    for (int r = 0; r < 4; r++) {
        red[((w * 4 + 0) * 16 + jcol) * 17 + rb + r] = acc_r[r];
        red[((w * 4 + 1) * 16 + jcol) * 17 + rb + r] = acc_z[r];
        red[((w * 4 + 2) * 16 + jcol) * 17 + rb + r] = acc_in[r];
        red[((w * 4 + 3) * 16 + jcol) * 17 + rb + r] = acc_hn[r];
    }
    __syncthreads();

    if (tid < 256) {
        int jj = tid >> 4, bl = tid & 15;
        float sr = 0, sz = 0, sin_ = 0, shn = 0;
        #pragma unroll
        for (int w2 = 0; w2 < 8; w2++) {
            sr   += red[((w2 * 4 + 0) * 16 + jj) * 17 + bl];
            sz   += red[((w2 * 4 + 1) * 16 + jj) * 17 + bl];
            sin_ += red[((w2 * 4 + 2) * 16 + jj) * 17 + bl];
            shn  += red[((w2 * 4 + 3) * 16 + jj) * 17 + bl];
        }
        int j = jt * 16 + jj, b = bt * 16 + bl;
        float r  = sigm(sr + ldf(b_ih, j) + ldf(b_hh, j));
        float zz = sigm(sz + ldf(b_ih, j + 256) + ldf(b_hh, j + 256));
        float n  = tanhf(sin_ + ldf(b_ih, j + 512) + r * (shn + ldf(b_hh, j + 512)));
        float hp = b2f(h_prev[(size_t)b * HID + j]);
        h_new[(size_t)b * HID + j] = f2b((1.f - zz) * n + zz * hp);
    }
}

__global__ __launch_bounds__(512) void gru_kernel(
    const u16* x, const u16* h_prev, u16* h_new,
    const u16* w_ih, const u16* w_hh,
    const void* b_ih, const void* b_hh, const int* flagp)
{
    if (*flagp) gru_body(x, h_prev, h_new, w_ih, w_hh, (const u16*)b_ih, (const u16*)b_hh);
    else        gru_body(x, h_prev, h_new, w_ih, w_hh, (const float*)b_ih, (const float*)b_hh);
}

// ---------------- final classifier
template <typename T>
__device__ void gen_body(const u16* hs, const T* gen_w, const T* gen_b, void* out) {
    int rowid = blockIdx.x;
    int b = rowid / NSTEPS, s = rowid % NSTEPS;
    const u16* h = hs + ((size_t)(s + 1) * NB + b) * HID;
    extern __shared__ float hsd[];
    int tid = threadIdx.x;
    for (int i = tid; i < HID; i += 64) hsd[i] = b2f(h[i]);
    __syncthreads();
    if (tid < NCLS) {
        float acc = ldf(gen_b, tid);
        const T* wr = gen_w + (size_t)tid * HID;
        #pragma unroll 4
        for (int k4 = 0; k4 < HID / 4; k4++) {
            float4 wv = ld4(wr + 4 * k4);
            acc += hsd[4 * k4 + 0] * wv.x + hsd[4 * k4 + 1] * wv.y
                 + hsd[4 * k4 + 2] * wv.z + hsd[4 * k4 + 3] * wv.w;
        }
        size_t o = (size_t)rowid * NCLS + tid;
        if (sizeof(T) == 2) ((u16*)out)[o] = f2b(acc);
        else                ((float*)out)[o] = acc;
    }
}
__global__ __launch_bounds__(64) void gen_kernel(
    const u16* hs, const void* gen_w, const void* gen_b, void* out, const int* flagp)
{
    if (*flagp) gen_body(hs, (const u16*)gen_w, (const u16*)gen_b, out);
    else        gen_body(hs, (const float*)gen_w, (const float*)gen_b, out);
}

extern "C" void kernel_launch(void* const* d_in, const int* in_sizes, int n_in,
                              void* d_out, int out_size, void* d_ws, size_t ws_size,
                              hipStream_t stream) {
    (void)in_sizes; (void)n_in; (void)out_size;
    const int* text = (const int*)d_in[6];

    char* ws = (char*)d_ws;
    size_t off = 256;
    int* flag = (int*)ws;
    u16* fp = (u16*)(ws + off); off += (size_t)NB * NT * HID * 2;        // 16.78 MB
    u16* ft = (u16*)(ws + off); off += (size_t)NB * NC * NT * 2;         // 33.55 MB
    u16* hs     = (u16*)(ws + off); off += 3407872;
    u16* x      = (u16*)(ws + off); off += 753664;
    u16* wih_c  = (u16*)(ws + off); off += 2260992;
    u16* whh_c  = (u16*)(ws + off); off += 393216;
    u16* h2h_wT = (u16*)(ws + off); off += 131072;

    probe_kernel<<<1, 128, 0, stream>>>(d_in[10], flag);
    conv_kernel<<<512, 256, 0, stream>>>(d_in[13], d_in[14], d_in[8],
                                         wih_c, whh_c, h2h_wT, flag);
    hipMemsetAsync(hs, 0, (size_t)NB * HID * 2, stream);  // h0 = 0
    fp_kernel<<<dim3(256, 2), 256, 0, stream>>>(d_in[0], d_in[7], fp, flag);
    trans_kernel<<<dim3(NB, NT / 8), 256, 0, stream>>>(d_in[0], ft, flag);

    for (int s = 0; s < NSTEPS; s++) {
        attn_kernel<<<NB, 512, 8728, stream>>>(
            d_in[1], d_in[2], d_in[3], d_in[4], text,
            d_in[9], d_in[10], d_in[11], d_in[12], d_in[17],
            h2h_wT, ft, fp, hs + (size_t)s * NB * HID, x, s, flag);
        gru_kernel<<<dim3(16, 16), 512, 34816, stream>>>(
            x, hs + (size_t)s * NB * HID, hs + (size_t)(s + 1) * NB * HID,
            wih_c, whh_c, d_in[15], d_in[16], flag);
    }
    gen_kernel<<<NB * NSTEPS, 64, 1024, stream>>>(hs, d_in[18], d_in[19], d_out, flag);
}